// Round 3
// baseline (309.059 us; speedup 1.0000x reference)
//
#include <hip/hip_runtime.h>

// InnerSelfAttention (sliding-window causal, WIN=256, unscaled QK^T) for MI355X.
// R2 (re-run; R2 bench failed with GPUAcquisitionTimeout — no counters):
//     fused QKV projection GEMM (N=3072, 768 blocks -> 3 blocks/CU),
//     global_load_lds width-16 staging (m97 structure), fused convert kernel.
// B=2 S=2048 E=1024 H=16 D=64 WIN=256.

typedef __bf16 bf16x8 __attribute__((ext_vector_type(8)));
typedef short s16x8 __attribute__((ext_vector_type(8)));
typedef float f32x4 __attribute__((ext_vector_type(4)));
typedef unsigned short u16;
typedef unsigned long long u64;

#define DEV __device__ __forceinline__

DEV u16 f2bf(float f) {  // RNE float->bf16
  unsigned u = __builtin_bit_cast(unsigned, f);
  u += 0x7FFFu + ((u >> 16) & 1u);
  return (u16)(u >> 16);
}
DEV float bf2f(u16 h) {
  unsigned u = ((unsigned)h) << 16;
  return __builtin_bit_cast(float, u);
}

#define MFMA16(a, b, c) __builtin_amdgcn_mfma_f32_16x16x32_bf16((a), (b), (c), 0, 0, 0)

// async global->LDS, 16B per lane. LDS dest is wave-uniform base + lane*16.
DEV void gload16(const u16* g, u16* l) {
  __builtin_amdgcn_global_load_lds(
      (const __attribute__((address_space(1))) void*)(const void*)g,
      (__attribute__((address_space(3))) void*)(void*)l, 16, 0, 0);
}

// stage a 128x32 bf16 tile (8 KB) from g[r0..r0+127][k0..k0+31] (row stride
// `stride` elems) into flat LDS [128][32]. 2 gloads per thread.
DEV void stage_tile(const u16* __restrict__ g, size_t stride, int r0, int k0,
                    u16* lds, int w, int lane) {
#pragma unroll
  for (int c = 0; c < 2; ++c) {
    int ch = c * 256 + (w << 6) + lane;  // 16B-chunk id, 0..511
    gload16(&g[(size_t)(r0 + (ch >> 2)) * stride + k0 + ((ch & 3) << 3)],
            lds + (size_t)(c * 4 + w) * 512);
  }
}

// ---------------- fused convert / split kernel ----------------
// regions (f32x4 units): x[0,1M) -> xh/xl; Wq[1M,1.25M) -> wh0/wl0;
// Wk -> wh+1M/wl+1M; Wv -> wh+2M (hi only); Wo -> woh (hi only).
__global__ __launch_bounds__(256) void cvt_all(
    const float* __restrict__ x, const float* __restrict__ Wq,
    const float* __restrict__ Wk, const float* __restrict__ Wv,
    const float* __restrict__ Wo, u16* __restrict__ xh, u16* __restrict__ xl,
    u16* __restrict__ wh, u16* __restrict__ wl, u16* __restrict__ woh) {
  for (int i = blockIdx.x * 256 + threadIdx.x; i < 2097152;
       i += gridDim.x * 256) {
    const float* src;
    u16 *dh, *dl = nullptr;
    int off;
    bool sp;
    if (i < 1048576) {
      src = x; off = i; dh = xh; dl = xl; sp = true;
    } else {
      int j = i - 1048576;
      int r = j >> 18;
      off = j & 262143;
      if (r == 0)      { src = Wq; dh = wh;           dl = wl;           sp = true; }
      else if (r == 1) { src = Wk; dh = wh + 1048576; dl = wl + 1048576; sp = true; }
      else if (r == 2) { src = Wv; dh = wh + 2097152; sp = false; }
      else             { src = Wo; dh = woh;          sp = false; }
    }
    f32x4 v = ((const f32x4*)src)[off];
    u64 ph = 0, pl = 0;
#pragma unroll
    for (int c = 0; c < 4; ++c) {
      u16 h = f2bf(v[c]);
      ph |= ((u64)h) << (16 * c);
      u16 l = f2bf(v[c] - bf2f(h));
      pl |= ((u64)l) << (16 * c);
    }
    ((u64*)dh)[off] = ph;
    if (sp) ((u64*)dl)[off] = pl;
  }
}

// ---------------- fused QKV GEMM -------------------------------------------
// C[4096][3072] = x[4096][1024] . W[3072][1024]^T, bf16x3 for Q/K regions,
// single bf16 for V region. Epilogue scatters per region.
__global__ __launch_bounds__(256, 3) void qkv_gemm(
    const u16* __restrict__ Xh, const u16* __restrict__ Xl,
    const u16* __restrict__ Wh, const u16* __restrict__ Wl,
    u16* __restrict__ qh, u16* __restrict__ ql, u16* __restrict__ kh,
    u16* __restrict__ kl, u16* __restrict__ vT) {
  __shared__ u16 sAh[128 * 32], sAl[128 * 32];
  __shared__ u16 sBh[128 * 32], sBl[128 * 32];
  const int tid = threadIdx.x, lane = tid & 63, w = tid >> 6;
  const int lr = lane & 15, lg = lane >> 4;
  const int wr = w >> 1, wc = w & 1;
  const int m0 = blockIdx.y * 128, n0 = blockIdx.x * 128;
  const int region = n0 >> 10;  // 0=Q 1=K 2=V
  const bool split = region < 2;

  f32x4 acc[4][4];
#pragma unroll
  for (int i = 0; i < 4; ++i)
#pragma unroll
    for (int j = 0; j < 4; ++j)
#pragma unroll
      for (int e = 0; e < 4; ++e) acc[i][j][e] = 0.f;

  for (int k0 = 0; k0 < 1024; k0 += 32) {
    stage_tile(Xh, 1024, m0, k0, sAh, w, lane);
    stage_tile(Wh, 1024, n0, k0, sBh, w, lane);
    if (split) {
      stage_tile(Xl, 1024, m0, k0, sAl, w, lane);
      stage_tile(Wl, 1024, n0, k0, sBl, w, lane);
    }
    __syncthreads();

    bf16x8 fah[4], fbh[4], fal[4], fbl[4];
#pragma unroll
    for (int f = 0; f < 4; ++f) {
      fah[f] = *(const bf16x8*)&sAh[(wr * 64 + f * 16 + lr) * 32 + lg * 8];
      fbh[f] = *(const bf16x8*)&sBh[(wc * 64 + f * 16 + lr) * 32 + lg * 8];
    }
    if (split) {
#pragma unroll
      for (int f = 0; f < 4; ++f) {
        fal[f] = *(const bf16x8*)&sAl[(wr * 64 + f * 16 + lr) * 32 + lg * 8];
        fbl[f] = *(const bf16x8*)&sBl[(wc * 64 + f * 16 + lr) * 32 + lg * 8];
      }
#pragma unroll
      for (int i = 0; i < 4; ++i)
#pragma unroll
        for (int j = 0; j < 4; ++j) {
          acc[i][j] = MFMA16(fah[i], fbh[j], acc[i][j]);
          acc[i][j] = MFMA16(fah[i], fbl[j], acc[i][j]);
          acc[i][j] = MFMA16(fal[i], fbh[j], acc[i][j]);
        }
    } else {
#pragma unroll
      for (int i = 0; i < 4; ++i)
#pragma unroll
        for (int j = 0; j < 4; ++j)
          acc[i][j] = MFMA16(fah[i], fbh[j], acc[i][j]);
    }
    __syncthreads();
  }

// epilogue. C layout (m89): col = lane&15, row = (lane>>4)*4 + e
#pragma unroll
  for (int i = 0; i < 4; ++i)
#pragma unroll
    for (int j = 0; j < 4; ++j)
#pragma unroll
      for (int e = 0; e < 4; ++e) {
        float v = acc[i][j][e];
        int mm = m0 + wr * 64 + i * 16 + lg * 4 + e;
        int nl = (n0 & 1023) + wc * 64 + j * 16 + lr;
        int bb = mm >> 11, ss = mm & 2047, hh = nl >> 6, dd = nl & 63;
        if (region == 0) {
          size_t idx = ((size_t)(bb * 16 + hh) * 2048 + ss) * 64 + dd;
          u16 h = f2bf(v);
          qh[idx] = h;
          ql[idx] = f2bf(v - bf2f(h));
        } else if (region == 1) {
          size_t idx = ((size_t)(bb * 16 + hh) * 2048 + ss) * 64 + dd;
          u16 h = f2bf(v);
          kh[idx] = h;
          kl[idx] = f2bf(v - bf2f(h));
        } else {
          vT[((size_t)(bb * 16 + hh) * 64 + dd) * 2048 + ss] = f2bf(v);
        }
      }
}

// ---------------- O-projection GEMM ----------------------------------------
__global__ __launch_bounds__(256) void out_gemm(const u16* __restrict__ ctx,
                                                const u16* __restrict__ Wo,
                                                const float* __restrict__ bias,
                                                float* __restrict__ Of) {
  __shared__ u16 sA[128 * 32], sB[128 * 32];
  const int tid = threadIdx.x, lane = tid & 63, w = tid >> 6;
  const int lr = lane & 15, lg = lane >> 4;
  const int wr = w >> 1, wc = w & 1;
  const int m0 = blockIdx.y * 128, n0 = blockIdx.x * 128;

  f32x4 acc[4][4];
#pragma unroll
  for (int i = 0; i < 4; ++i)
#pragma unroll
    for (int j = 0; j < 4; ++j)
#pragma unroll
      for (int e = 0; e < 4; ++e) acc[i][j][e] = 0.f;

  for (int k0 = 0; k0 < 1024; k0 += 32) {
    stage_tile(ctx, 1024, m0, k0, sA, w, lane);
    stage_tile(Wo, 1024, n0, k0, sB, w, lane);
    __syncthreads();
    bf16x8 fa[4], fb[4];
#pragma unroll
    for (int f = 0; f < 4; ++f) {
      fa[f] = *(const bf16x8*)&sA[(wr * 64 + f * 16 + lr) * 32 + lg * 8];
      fb[f] = *(const bf16x8*)&sB[(wc * 64 + f * 16 + lr) * 32 + lg * 8];
    }
#pragma unroll
    for (int i = 0; i < 4; ++i)
#pragma unroll
      for (int j = 0; j < 4; ++j) acc[i][j] = MFMA16(fa[i], fb[j], acc[i][j]);
    __syncthreads();
  }
#pragma unroll
  for (int i = 0; i < 4; ++i)
#pragma unroll
    for (int j = 0; j < 4; ++j)
#pragma unroll
      for (int e = 0; e < 4; ++e) {
        int mm = m0 + wr * 64 + i * 16 + lg * 4 + e;
        int nn = n0 + wc * 64 + j * 16 + lr;
        Of[(size_t)mm * 1024 + nn] = acc[i][j][e] + bias[nn];
      }
}

// ---------------- flash attention, 64-query blocks, 64-key tiles ------------
__global__ __launch_bounds__(256) void attn_kernel(
    const u16* __restrict__ qh, const u16* __restrict__ ql,
    const u16* __restrict__ kh, const u16* __restrict__ kl,
    const u16* __restrict__ vT, u16* __restrict__ ctx) {
  const int qt = blockIdx.x, hd = blockIdx.y, b = blockIdx.z;
  const int q0 = qt * 64;
  const int bh = b * 16 + hd;
  const int tid = threadIdx.x;
  const int lane = tid & 63, w = tid >> 6;
  const int lr = lane & 15, lg = lane >> 4;

  __shared__ u16 sKh[64][72];  // [key][d], 144B rows -> 2-way alias
  __shared__ u16 sKl[64][72];
  __shared__ u16 sVT[64][72];  // [d][key]
  __shared__ u16 sP[4][16][72];  // per-wave P tile [q][key]

  bf16x8 qfh[2], qfl[2];
  const size_t qbase = ((size_t)bh * 2048 + q0 + w * 16 + lr) * 64;
#pragma unroll
  for (int ks = 0; ks < 2; ++ks) {
    qfh[ks] = *(const bf16x8*)&qh[qbase + ks * 32 + lg * 8];
    qfl[ks] = *(const bf16x8*)&ql[qbase + ks * 32 + lg * 8];
  }

  float mrow[4], lrow[4];
  f32x4 cf[4];
#pragma unroll
  for (int e = 0; e < 4; ++e) { mrow[e] = -__builtin_inff(); lrow[e] = 0.f; }
#pragma unroll
  for (int nd = 0; nd < 4; ++nd)
#pragma unroll
    for (int e = 0; e < 4; ++e) cf[nd][e] = 0.f;

  const int t0 = (qt >= 4) ? qt - 4 : 0;
  for (int t = t0; t <= qt; ++t) {
    const int k0 = t * 64;
#pragma unroll
    for (int c = 0; c < 2; ++c) {
      int cid = c * 256 + tid;
      int row = cid >> 3, col8 = (cid & 7) * 8;
      size_t kidx = ((size_t)bh * 2048 + k0 + row) * 64 + col8;
      size_t vidx = ((size_t)bh * 64 + row) * 2048 + k0 + col8;
      *(s16x8*)&sKh[row][col8] = *(const s16x8*)&kh[kidx];
      *(s16x8*)&sKl[row][col8] = *(const s16x8*)&kl[kidx];
      *(s16x8*)&sVT[row][col8] = *(const s16x8*)&vT[vidx];
    }
    __syncthreads();

    f32x4 sc[4];
#pragma unroll
    for (int nf = 0; nf < 4; ++nf)
#pragma unroll
      for (int e = 0; e < 4; ++e) sc[nf][e] = 0.f;
#pragma unroll
    for (int ks = 0; ks < 2; ++ks)
#pragma unroll
      for (int nf = 0; nf < 4; ++nf) {
        bf16x8 kbh = *(const bf16x8*)&sKh[nf * 16 + lr][ks * 32 + lg * 8];
        bf16x8 kbl = *(const bf16x8*)&sKl[nf * 16 + lr][ks * 32 + lg * 8];
        sc[nf] = MFMA16(qfh[ks], kbh, sc[nf]);
        sc[nf] = MFMA16(qfh[ks], kbl, sc[nf]);
        sc[nf] = MFMA16(qfl[ks], kbh, sc[nf]);
      }

    const bool masked = (k0 < q0 - 192) || (k0 >= q0);
    if (masked) {
#pragma unroll
      for (int nf = 0; nf < 4; ++nf) {
        int key = k0 + nf * 16 + lr;
#pragma unroll
        for (int e = 0; e < 4; ++e) {
          int qi = q0 + w * 16 + lg * 4 + e;
          if (key > qi || key + 256 <= qi) sc[nf][e] = -__builtin_inff();
        }
      }
    }

    float rm[4];
#pragma unroll
    for (int e = 0; e < 4; ++e)
      rm[e] = fmaxf(fmaxf(sc[0][e], sc[1][e]), fmaxf(sc[2][e], sc[3][e]));
#pragma unroll
    for (int off = 1; off < 16; off <<= 1)
#pragma unroll
      for (int e = 0; e < 4; ++e) rm[e] = fmaxf(rm[e], __shfl_xor(rm[e], off));

    float alpha[4], mu[4];
#pragma unroll
    for (int e = 0; e < 4; ++e) {
      float mn = fmaxf(mrow[e], rm[e]);
      bool ninf = (mn == -__builtin_inff());
      mu[e] = ninf ? 0.f : mn;
      alpha[e] = ninf ? 1.f : __expf(mrow[e] - mn);
      mrow[e] = mn;
    }
    float p[4][4], rs[4];
#pragma unroll
    for (int nf = 0; nf < 4; ++nf)
#pragma unroll
      for (int e = 0; e < 4; ++e) p[nf][e] = __expf(sc[nf][e] - mu[e]);
#pragma unroll
    for (int e = 0; e < 4; ++e) rs[e] = p[0][e] + p[1][e] + p[2][e] + p[3][e];
#pragma unroll
    for (int off = 1; off < 16; off <<= 1)
#pragma unroll
      for (int e = 0; e < 4; ++e) rs[e] += __shfl_xor(rs[e], off);
#pragma unroll
    for (int e = 0; e < 4; ++e) lrow[e] = lrow[e] * alpha[e] + rs[e];
#pragma unroll
    for (int nd = 0; nd < 4; ++nd)
#pragma unroll
      for (int e = 0; e < 4; ++e) cf[nd][e] *= alpha[e];

#pragma unroll
    for (int nf = 0; nf < 4; ++nf)
#pragma unroll
      for (int e = 0; e < 4; ++e)
        sP[w][lg * 4 + e][nf * 16 + lr] = f2bf(p[nf][e]);

#pragma unroll
    for (int ks = 0; ks < 2; ++ks) {
      bf16x8 pa = *(const bf16x8*)&sP[w][lr][ks * 32 + lg * 8];
#pragma unroll
      for (int nd = 0; nd < 4; ++nd) {
        bf16x8 vb = *(const bf16x8*)&sVT[nd * 16 + lr][ks * 32 + lg * 8];
        cf[nd] = MFMA16(pa, vb, cf[nd]);
      }
    }
    __syncthreads();
  }

#pragma unroll
  for (int nd = 0; nd < 4; ++nd)
#pragma unroll
    for (int e = 0; e < 4; ++e) {
      float v = cf[nd][e] / lrow[e];
      size_t o = ((size_t)(b * 2048 + q0 + w * 16 + lg * 4 + e)) * 1024 +
                 hd * 64 + nd * 16 + lr;
      ctx[o] = f2bf(v);
    }
}

// ---------------- launch ----------------
extern "C" void kernel_launch(void* const* d_in, const int* in_sizes, int n_in,
                              void* d_out, int out_size, void* d_ws, size_t ws_size,
                              hipStream_t stream) {
  (void)in_sizes; (void)n_in; (void)out_size; (void)ws_size;
  const float* x  = (const float*)d_in[0];
  const float* Wq = (const float*)d_in[1];
  const float* Wk = (const float*)d_in[2];
  const float* Wv = (const float*)d_in[3];
  const float* Wo = (const float*)d_in[4];
  const float* bo = (const float*)d_in[5];
  float* out = (float*)d_out;
  char* ws = (char*)d_ws;

  constexpr size_t MB = 1048576;
  u16* xh  = (u16*)(ws + 0 * MB);
  u16* xl  = (u16*)(ws + 8 * MB);
  u16* qh  = (u16*)(ws + 16 * MB);
  u16* ql  = (u16*)(ws + 24 * MB);
  u16* kh  = (u16*)(ws + 32 * MB);
  u16* kl  = (u16*)(ws + 40 * MB);
  u16* vT  = (u16*)(ws + 48 * MB);
  u16* ctx = (u16*)(ws + 56 * MB);
  u16* wh  = (u16*)(ws + 64 * MB);  // 3072x1024 hi (Wq,Wk,Wv)
  u16* wl  = (u16*)(ws + 70 * MB);  // 2048x1024 lo (Wq,Wk)
  u16* woh = (u16*)(ws + 74 * MB);  // 1024x1024 hi

  cvt_all<<<2048, 256, 0, stream>>>(x, Wq, Wk, Wv, Wo, xh, xl, wh, wl, woh);
  qkv_gemm<<<dim3(24, 32), 256, 0, stream>>>(xh, xl, wh, wl, qh, ql, kh, kl, vT);
  attn_kernel<<<dim3(32, 16, 2), 256, 0, stream>>>(qh, ql, kh, kl, vT, ctx);
  out_gemm<<<dim3(8, 32), 256, 0, stream>>>(ctx, woh, bo, out);
}